// Round 2
// baseline (12379.038 us; speedup 1.0000x reference)
//
#include <hip/hip_runtime.h>
#include <hip/hip_cooperative_groups.h>
#include <cmath>

namespace cg = cooperative_groups;

#define TSTEPS 256
#define BATCH 64
#define DIM 1024
#define WSTRIDE 2056   // 2048 + 8 halfs pad
#define GSTRIDE 17     // 16 + 1 pad for gate scratch

typedef _Float16 half8v __attribute__((ext_vector_type(8)));
typedef _Float16 half4v __attribute__((ext_vector_type(4)));
typedef float f32x4 __attribute__((ext_vector_type(4)));

// ws layout (halfs):
//   xh   : [B][T][D] fp16 copy of x, 16,777,216 halfs at offset 0
//   hbuf : [2 parity][2 layer][B][H]  262,144 halfs after xh
// Phase p: reads parity p&1 (h0_{p-1}, h1_{p-2}), writes parity (p+1)&1.

__global__ void prologue(const float* __restrict__ x, _Float16* __restrict__ xh,
                         _Float16* __restrict__ hbuf)
{
    size_t gid  = (size_t)blockIdx.x * blockDim.x + threadIdx.x;
    size_t nthr = (size_t)gridDim.x * blockDim.x;
    for (size_t i = gid; i < 4194304u; i += nthr) {   // 16.7M floats as float4
        float4 v = ((const float4*)x)[i];
        half4v h = {(_Float16)v.x, (_Float16)v.y, (_Float16)v.z, (_Float16)v.w};
        ((half4v*)xh)[i] = h;
    }
    for (size_t i = gid; i < 32768u; i += nthr) {     // zero 262,144 halfs
        half8v z = {};
        ((half8v*)hbuf)[i] = z;
    }
}

// 256 blocks (1/CU) x 512 threads (8 waves).
// Block b owns h-dims [4b,4b+4) for both layers => 16 gate-cols/layer in LDS.
// Waves 0-3: layer-0 cell (M-tiles 0..3 of batch). Waves 4-7: layer-1 cell.
__global__ __launch_bounds__(512, 1)
void lstm_persistent(const float* __restrict__ Wx0, const float* __restrict__ Wh0,
                     const float* __restrict__ b0,
                     const float* __restrict__ Wx1, const float* __restrict__ Wh1,
                     const float* __restrict__ b1,
                     const _Float16* __restrict__ xh, _Float16* __restrict__ hbuf,
                     float* __restrict__ out)
{
    extern __shared__ char smem[];
    _Float16* w0s  = (_Float16*)smem;                       // [16][WSTRIDE] K=[x|h0]
    _Float16* w1s  = w0s + 16 * WSTRIDE;                    // [16][WSTRIDE] K=[h0|h1]
    float*    gates = (float*)(smem + (size_t)2 * 16 * WSTRIDE * 2); // [2][64][GSTRIDE]
    float*    cst   = gates + 2 * 64 * GSTRIDE;             // [512] c-state

    const int tid = threadIdx.x;
    const int blk = blockIdx.x;

    // ---- one-time: weight slices -> LDS (fp32 -> fp16) ----
    const float* mats[4] = {Wx0, Wh0, Wx1, Wh1};
    for (int idx = tid; idx < 16384; idx += 512) {
        int mat = idx >> 12, g = (idx >> 10) & 3, k = idx & 1023;
        const float4* src = (const float4*)(mats[mat] + (size_t)k * 4096 + g * 1024 + blk * 4);
        float4 v = *src;
        _Float16* dst = (mat < 2) ? w0s : w1s;
        int koff = ((mat & 1) << 10) + k;
        dst[(g * 4 + 0) * WSTRIDE + koff] = (_Float16)v.x;
        dst[(g * 4 + 1) * WSTRIDE + koff] = (_Float16)v.y;
        dst[(g * 4 + 2) * WSTRIDE + koff] = (_Float16)v.z;
        dst[(g * 4 + 3) * WSTRIDE + koff] = (_Float16)v.w;
    }
    cst[tid] = 0.0f;

    // pointwise thread mapping: (cell, batch, dim)
    const int pcell = tid >> 8, pb = (tid >> 2) & 63, pd = tid & 3;
    const float* bias = pcell ? b1 : b0;
    const int gdim = blk * 4 + pd;
    const float bi = bias[0 * 1024 + gdim], bfg = bias[1 * 1024 + gdim],
                bg = bias[2 * 1024 + gdim], bo  = bias[3 * 1024 + gdim];

    __syncthreads();

    cg::grid_group grid = cg::this_grid();

    const int wave = tid >> 6, lane = tid & 63;
    const int cell = wave >> 2, mrow0 = (wave & 3) * 16;
    const int n15 = lane & 15;            // A-row within tile / B-col / C-col
    const int kq  = (lane >> 4) << 3;     // per-lane K sub-offset (quad*8)
    const int bm  = mrow0 + n15;          // batch row

    for (int p = 0; p <= TSTEPS; ++p) {
        const int rd = p & 1, wr = rd ^ 1;

        const bool gemm_active = cell ? (p >= 1) : (p < TSTEPS);
        if (gemm_active) {
            f32x4 acc = {0.f, 0.f, 0.f, 0.f};
            // B fragment: lane holds B[k = quad*8 + j][n = lane&15] -> needs +kq too!
            const _Float16* wrow = (cell ? w1s : w0s) + (size_t)n15 * WSTRIDE + kq;
            const _Float16 *a0, *a1;
            if (cell == 0) {
                a0 = xh + ((size_t)bm * TSTEPS + p) * DIM + kq;           // x_t
                a1 = hbuf + rd * 131072 + 0 * 65536 + bm * 1024 + kq;     // h0_{p-1}
            } else {
                a0 = hbuf + rd * 131072 + 0 * 65536 + bm * 1024 + kq;     // h0_{p-1}
                a1 = hbuf + rd * 131072 + 1 * 65536 + bm * 1024 + kq;     // h1_{p-2}
            }
            #pragma unroll 8
            for (int kt = 0; kt < 32; ++kt) {
                half8v av = *(const half8v*)(a0 + kt * 32);
                half8v bv = *(const half8v*)(wrow + kt * 32);
                acc = __builtin_amdgcn_mfma_f32_16x16x32_f16(av, bv, acc, 0, 0, 0);
            }
            #pragma unroll 8
            for (int kt = 0; kt < 32; ++kt) {
                half8v av = *(const half8v*)(a1 + kt * 32);
                half8v bv = *(const half8v*)(wrow + 1024 + kt * 32);
                acc = __builtin_amdgcn_mfma_f32_16x16x32_f16(av, bv, acc, 0, 0, 0);
            }
            // C frag: col = lane&15, row = (lane>>4)*4 + r
            float* gs = gates + cell * (64 * GSTRIDE);
            int row0 = mrow0 + ((lane >> 4) << 2);
            #pragma unroll
            for (int r = 0; r < 4; ++r)
                gs[(row0 + r) * GSTRIDE + n15] = acc[r];
        }
        __syncthreads();

        const bool pw_active = pcell ? (p >= 1) : (p < TSTEPS);
        if (pw_active) {
            const float* gs = gates + pcell * (64 * GSTRIDE) + pb * GSTRIDE;
            float gi = gs[0 * 4 + pd] + bi;
            float gf = gs[1 * 4 + pd] + bfg;
            float gg = gs[2 * 4 + pd] + bg;
            float go = gs[3 * 4 + pd] + bo;
            float si = 1.f / (1.f + __expf(-gi));
            float sf = 1.f / (1.f + __expf(-gf));
            float so = 1.f / (1.f + __expf(-go));
            float cn = sf * cst[tid] + si * tanhf(gg);
            float hn = so * tanhf(cn);
            cst[tid] = cn;
            hbuf[wr * 131072 + pcell * 65536 + pb * 1024 + gdim] = (_Float16)hn;
            if (pcell && p == TSTEPS) out[pb * 1024 + gdim] = hn;  // t=255 output
        }
        grid.sync();
    }
}

extern "C" void kernel_launch(void* const* d_in, const int* in_sizes, int n_in,
                              void* d_out, int out_size, void* d_ws, size_t ws_size,
                              hipStream_t stream)
{
    const float* x   = (const float*)d_in[0];
    const float* Wx0 = (const float*)d_in[1];
    const float* Wh0 = (const float*)d_in[2];
    const float* b0  = (const float*)d_in[3];
    const float* Wx1 = (const float*)d_in[4];
    const float* Wh1 = (const float*)d_in[5];
    const float* b1  = (const float*)d_in[6];
    float* out = (float*)d_out;

    _Float16* xh   = (_Float16*)d_ws;
    _Float16* hbuf = xh + (size_t)16777216;   // needs ~34.1 MB of ws total

    hipLaunchKernelGGL(prologue, dim3(2048), dim3(256), 0, stream, x, xh, hbuf);

    size_t smem = (size_t)2 * 16 * WSTRIDE * 2   // weight slices (131,584 B)
                + (size_t)2 * 64 * GSTRIDE * 4   // gate scratch   (8,704 B)
                + 512 * 4;                       // c-state        (2,048 B)
    hipFuncSetAttribute((const void*)lstm_persistent,
                        hipFuncAttributeMaxDynamicSharedMemorySize, (int)smem);

    void* args[] = {(void*)&Wx0, (void*)&Wh0, (void*)&b0,
                    (void*)&Wx1, (void*)&Wh1, (void*)&b1,
                    (void*)&xh, (void*)&hbuf, (void*)&out};
    hipLaunchCooperativeKernel((const void*)lstm_persistent, dim3(256), dim3(512),
                               args, (unsigned)smem, stream);
}

// Round 3
// 7881.906 us; speedup vs baseline: 1.5706x; 1.5706x over previous
//
#include <hip/hip_runtime.h>
#include <cmath>

#define TSTEPS 256
#define DIM 1024
#define GSTRIDE 17

typedef _Float16 half8v __attribute__((ext_vector_type(8)));
typedef _Float16 half4v __attribute__((ext_vector_type(4)));
typedef float f32x4 __attribute__((ext_vector_type(4)));
typedef unsigned long long u64;

// ws layout (halfs):
//   xh    : [B][T][D] fp16 x, 16,777,216 halfs at offset 0
//   hbuf  : [2 parity][2 layer][64][1024], 262,144 halfs
//   flags : 256 uints (barrier), after hbuf
// Phase p: reads parity p&1 (h0_{p-1}, h1_{p-2}), writes parity (p+1)&1.

__global__ void prologue(const float* __restrict__ x, _Float16* __restrict__ xh,
                         _Float16* __restrict__ hbuf, unsigned* __restrict__ flags)
{
    size_t gid  = (size_t)blockIdx.x * blockDim.x + threadIdx.x;
    size_t nthr = (size_t)gridDim.x * blockDim.x;
    for (size_t i = gid; i < 4194304u; i += nthr) {
        float4 v = ((const float4*)x)[i];
        half4v h = {(_Float16)v.x, (_Float16)v.y, (_Float16)v.z, (_Float16)v.w};
        ((half4v*)xh)[i] = h;
    }
    for (size_t i = gid; i < 32768u; i += nthr) {
        half8v z = {};
        ((half8v*)hbuf)[i] = z;
    }
    if (gid < 256) flags[gid] = 0u;
}

__device__ __forceinline__ half8v load_h8_agent(const _Float16* p) {
    union { u64 u[2]; half8v v; } t;
    t.u[0] = __hip_atomic_load((const u64*)p,     __ATOMIC_RELAXED, __HIP_MEMORY_SCOPE_AGENT);
    t.u[1] = __hip_atomic_load((const u64*)p + 1, __ATOMIC_RELAXED, __HIP_MEMORY_SCOPE_AGENT);
    return t.v;
}

// 256 blocks (1/CU) x 512 threads (8 waves, 2/SIMD -> <=256 VGPR/wave).
// Block owns h-dims [4b,4b+4) for both layers (16 gate-cols/layer).
// Wave w: cell = w>>2, kq4 = w&3 (K-quarter of 512). Weights in REGISTERS
// (16 x half8v = 64 VGPR). Each wave does all 4 M-tiles; K-partials reduced
// through LDS fp32 gates, summed in the pointwise stage.
__global__ __launch_bounds__(512, 1)
void lstm_persistent(const float* __restrict__ Wx0, const float* __restrict__ Wh0,
                     const float* __restrict__ b0,
                     const float* __restrict__ Wx1, const float* __restrict__ Wh1,
                     const float* __restrict__ b1,
                     const _Float16* __restrict__ xh, _Float16* __restrict__ hbuf,
                     unsigned* __restrict__ flags, float* __restrict__ out)
{
    extern __shared__ char smem[];
    _Float16* wfrag = (_Float16*)smem;             // [2][64][64][8] halfs = 128 KB (dead after init)
    float*    gates = (float*)smem;                 // [8][64][GSTRIDE] fp32 (aliases wfrag)
    float*    cst   = gates + 8 * 64 * GSTRIDE;     // [512]

    const int tid = threadIdx.x;
    const int blk = blockIdx.x;
    const int lane = tid & 63, wave = tid >> 6;
    const int cell = wave >> 2, kq4 = wave & 3;
    const int n15 = lane & 15, q = lane >> 4;

    // ---- one-time: weights -> LDS in MFMA B-fragment order (fp32->fp16) ----
    const float* mats[4] = {Wx0, Wh0, Wx1, Wh1};
    for (int idx = tid; idx < 16384; idx += 512) {
        int mat = idx >> 12, g = (idx >> 10) & 3, k = idx & 1023;
        float4 v = *(const float4*)(mats[mat] + (size_t)k * 4096 + g * 1024 + blk * 4);
        int mcell = mat >> 1, kh = mat & 1;
        int kt64 = kh * 32 + (k >> 5), qq = (k >> 3) & 3, j = k & 7;
        int lbase = ((mcell * 64 + kt64) * 64 + qq * 16 + g * 4) * 8 + j;
        wfrag[lbase + 0 * 8] = (_Float16)v.x;
        wfrag[lbase + 1 * 8] = (_Float16)v.y;
        wfrag[lbase + 2 * 8] = (_Float16)v.z;
        wfrag[lbase + 3 * 8] = (_Float16)v.w;
    }
    __syncthreads();

    // ---- weights LDS -> registers (64 VGPR/lane), conflict-free b128 ----
    half8v wreg[16];
    #pragma unroll
    for (int kt = 0; kt < 16; ++kt)
        wreg[kt] = *(const half8v*)&wfrag[((cell * 64 + kq4 * 16 + kt) * 64 + lane) * 8];
    __syncthreads();          // wfrag now dead; gates/cst alias it
    cst[tid] = 0.0f;

    // pointwise mapping: (cell, batch, dim)
    const int pcell = tid >> 8, pb = (tid >> 2) & 63, pd = tid & 3;
    const float* bias = pcell ? b1 : b0;
    const int gdim = blk * 4 + pd;
    const float bi = bias[0 * 1024 + gdim], bfg = bias[1 * 1024 + gdim],
                bg = bias[2 * 1024 + gdim], bo  = bias[3 * 1024 + gdim];
    __syncthreads();

    const bool use_x = (cell == 0) && (kq4 < 2);
    const int  layer = (cell == 0) ? 0 : (kq4 >> 1);      // which h buffer
    const int  koff  = (kq4 & 1) * 512;                   // k offset within matrix
    const int  kfrag = koff + q * 8;                      // + per-lane quad offset

    for (int p = 0; p <= TSTEPS; ++p) {
        const int rd = p & 1, wr = rd ^ 1;

        const bool gemm_active = cell ? (p >= 1) : (p < TSTEPS);
        if (gemm_active) {
            float* gs = gates + (kq4 * 2 + cell) * (64 * GSTRIDE);
            #pragma unroll
            for (int mt = 0; mt < 4; ++mt) {
                const int bm = mt * 16 + n15;
                f32x4 acc = {0.f, 0.f, 0.f, 0.f};
                if (use_x) {
                    const _Float16* a = xh + ((size_t)bm * TSTEPS + p) * DIM + kfrag;
                    #pragma unroll
                    for (int kt = 0; kt < 16; ++kt) {
                        half8v av = *(const half8v*)(a + kt * 32);
                        acc = __builtin_amdgcn_mfma_f32_16x16x32_f16(av, wreg[kt], acc, 0, 0, 0);
                    }
                } else {
                    const _Float16* a = hbuf + rd * 131072 + layer * 65536 + bm * 1024 + kfrag;
                    #pragma unroll
                    for (int kt = 0; kt < 16; ++kt) {
                        half8v av = load_h8_agent(a + kt * 32);
                        acc = __builtin_amdgcn_mfma_f32_16x16x32_f16(av, wreg[kt], acc, 0, 0, 0);
                    }
                }
                const int row0 = mt * 16 + q * 4;
                #pragma unroll
                for (int r = 0; r < 4; ++r)
                    gs[(row0 + r) * GSTRIDE + n15] = acc[r];
            }
        }
        __syncthreads();

        const bool pw_active = pcell ? (p >= 1) : (p < TSTEPS);
        if (pw_active) {
            float g0 = 0.f, g1 = 0.f, g2 = 0.f, g3 = 0.f;
            #pragma unroll
            for (int k4 = 0; k4 < 4; ++k4) {
                const float* gsr = gates + (k4 * 2 + pcell) * (64 * GSTRIDE) + pb * GSTRIDE;
                g0 += gsr[0 * 4 + pd]; g1 += gsr[1 * 4 + pd];
                g2 += gsr[2 * 4 + pd]; g3 += gsr[3 * 4 + pd];
            }
            g0 += bi; g1 += bfg; g2 += bg; g3 += bo;
            float si = 1.f / (1.f + __expf(-g0));
            float sf = 1.f / (1.f + __expf(-g1));
            float so = 1.f / (1.f + __expf(-g3));
            float cn = sf * cst[tid] + si * tanhf(g2);
            float hn = so * tanhf(cn);
            cst[tid] = cn;
            // pack 4 halfs (lanes pd=0..3) -> one 8-B agent-scope store
            float v0 = __shfl(hn, (lane & ~3) | 0);
            float v1 = __shfl(hn, (lane & ~3) | 1);
            float v2 = __shfl(hn, (lane & ~3) | 2);
            float v3 = __shfl(hn, (lane & ~3) | 3);
            if (pd == 0) {
                union { half4v h; u64 u; } t;
                t.h = half4v{(_Float16)v0, (_Float16)v1, (_Float16)v2, (_Float16)v3};
                __hip_atomic_store((u64*)(hbuf + wr * 131072 + pcell * 65536 + pb * 1024 + blk * 4),
                                   t.u, __ATOMIC_RELAXED, __HIP_MEMORY_SCOPE_AGENT);
            }
            if (pcell && p == TSTEPS) out[pb * 1024 + gdim] = hn;
        }

        if (p < TSTEPS) {
            // ---- lightweight global barrier (no L2 writeback) ----
            asm volatile("s_waitcnt vmcnt(0)" ::: "memory");  // own stores+loads done
            __syncthreads();                                   // whole block drained
            if (tid == 0)
                __hip_atomic_store(&flags[blk], (unsigned)(p + 1),
                                   __ATOMIC_RELAXED, __HIP_MEMORY_SCOPE_AGENT);
            if (tid < 256) {
                const unsigned target = (unsigned)(p + 1);
                while (__hip_atomic_load(&flags[tid], __ATOMIC_RELAXED,
                                         __HIP_MEMORY_SCOPE_AGENT) < target) {}
            }
            __syncthreads();
            asm volatile("" ::: "memory");
        }
    }
}

extern "C" void kernel_launch(void* const* d_in, const int* in_sizes, int n_in,
                              void* d_out, int out_size, void* d_ws, size_t ws_size,
                              hipStream_t stream)
{
    const float* x   = (const float*)d_in[0];
    const float* Wx0 = (const float*)d_in[1];
    const float* Wh0 = (const float*)d_in[2];
    const float* b0  = (const float*)d_in[3];
    const float* Wx1 = (const float*)d_in[4];
    const float* Wh1 = (const float*)d_in[5];
    const float* b1  = (const float*)d_in[6];
    float* out = (float*)d_out;

    _Float16* xh    = (_Float16*)d_ws;
    _Float16* hbuf  = xh + (size_t)16777216;
    unsigned* flags = (unsigned*)(hbuf + 262144);

    hipLaunchKernelGGL(prologue, dim3(2048), dim3(256), 0, stream, x, xh, hbuf, flags);

    size_t smem = 131072;   // wfrag (gates+cst alias inside it: 36,864 B live in loop)
    hipFuncSetAttribute((const void*)lstm_persistent,
                        hipFuncAttributeMaxDynamicSharedMemorySize, (int)smem);

    void* args[] = {(void*)&Wx0, (void*)&Wh0, (void*)&b0,
                    (void*)&Wx1, (void*)&Wh1, (void*)&b1,
                    (void*)&xh, (void*)&hbuf, (void*)&flags, (void*)&out};
    hipLaunchCooperativeKernel((const void*)lstm_persistent, dim3(256), dim3(512),
                               args, (unsigned)smem, stream);
}

// Round 5
// 7342.133 us; speedup vs baseline: 1.6860x; 1.0735x over previous
//
#include <hip/hip_runtime.h>
#include <cmath>

#define TSTEPS 256
#define DIM 1024
#define GST 35            // gate scratch col-stride (32+3): <=2-way LDS conflicts

typedef _Float16 half8v __attribute__((ext_vector_type(8)));
typedef _Float16 half4v __attribute__((ext_vector_type(4)));
typedef float f32x4 __attribute__((ext_vector_type(4)));
typedef unsigned long long u64;

// ws layout (halfs):
//   xh    : [B][T][D] fp16 x, 16,777,216 halfs at offset 0
//   hbuf  : [2 parity][2 layer][64][1024], 262,144 halfs
//   flags : 256 uints (barrier) after hbuf
// Phase p: reads parity p&1, writes parity (p+1)&1.

__global__ void prologue(const float* __restrict__ x, _Float16* __restrict__ xh,
                         _Float16* __restrict__ hbuf, unsigned* __restrict__ flags)
{
    size_t gid  = (size_t)blockIdx.x * blockDim.x + threadIdx.x;
    size_t nthr = (size_t)gridDim.x * blockDim.x;
    for (size_t i = gid; i < 4194304u; i += nthr) {
        float4 v = ((const float4*)x)[i];
        half4v h = {(_Float16)v.x, (_Float16)v.y, (_Float16)v.z, (_Float16)v.w};
        ((half4v*)xh)[i] = h;
    }
    for (size_t i = gid; i < 32768u; i += nthr) {
        half8v z = {};
        ((half8v*)hbuf)[i] = z;
    }
    if (gid < 256) flags[gid] = 0u;
}

// 256 blocks x 512 threads. Blocks 0..127: cell0 (K=[x|h0]); 128..255: cell1
// (K=[h0|h1]). Block owns 32 gate-cols = 8 h-dims (wb*8..wb*8+8), col-in-block
// cc = gate*8 + c. Wave kq (0..7) owns K-slice [kq*256, kq*256+256), holds its
// 32-col weight slice in registers (16 x half8v = 64 VGPR). h reads are PLAIN
// cached loads (L2-amplified); coherence via per-phase agent acquire fence
// (buffer_inv sc1). h writes are agent-scope write-through (no dirty L2 lines).
__global__ __launch_bounds__(512, 1)
void lstm_persistent(const float* __restrict__ Wx0, const float* __restrict__ Wh0,
                     const float* __restrict__ b0,
                     const float* __restrict__ Wx1, const float* __restrict__ Wh1,
                     const float* __restrict__ b1,
                     const _Float16* __restrict__ xh, _Float16* __restrict__ hbuf,
                     unsigned* __restrict__ flags, float* __restrict__ out)
{
    extern __shared__ char smem[];
    _Float16* wfrag = (_Float16*)smem;          // 128 KB staging (dead after init)
    float*    gates = (float*)smem;             // [8 kq][64 m][GST] fp32, aliases wfrag

    const int tid  = threadIdx.x;
    const int blk  = blockIdx.x;
    const int cell = blk >> 7;          // 0: layer-0 cell, 1: layer-1 cell
    const int wb   = blk & 127;         // dim-group within cell
    const int lane = tid & 63, kq = tid >> 6;   // wave index = K-slice
    const int n15 = lane & 15, q = lane >> 4;

    // ---- one-time: weights -> LDS in B-fragment order (fp32->fp16) ----
    const float* m0 = cell ? Wx1 : Wx0;   // K rows 0..1023
    const float* m1 = cell ? Wh1 : Wh0;   // K rows 1024..2047
    for (int idx = tid; idx < 16384; idx += 512) {
        int k = idx >> 3;                 // 0..2047
        int cc0 = (idx & 7) * 4;          // col-in-block base
        int g = cc0 >> 3, c = cc0 & 7;
        const float* src = (k < 1024 ? m0 + (size_t)k * 4096
                                     : m1 + (size_t)(k - 1024) * 4096)
                           + g * 1024 + wb * 8 + c;
        float4 v = *(const float4*)src;
        int skq = k >> 8, kt = (k >> 5) & 7, sq = (k >> 3) & 3, j = k & 7;
        float vv[4] = {v.x, v.y, v.z, v.w};
        #pragma unroll
        for (int e = 0; e < 4; ++e) {
            int cc = cc0 + e, nt = cc >> 4, nn = cc & 15;
            wfrag[((((skq * 2 + nt) * 8 + kt) * 64) + sq * 16 + nn) * 8 + j] = (_Float16)vv[e];
        }
    }
    __syncthreads();

    // ---- weights LDS -> registers (conflict-free b128) ----
    half8v wreg[16];                      // [nt*8 + kt]
    #pragma unroll
    for (int nt = 0; nt < 2; ++nt)
        #pragma unroll
        for (int kt = 0; kt < 8; ++kt)
            wreg[nt * 8 + kt] = *(const half8v*)
                &wfrag[((((kq * 2 + nt) * 8 + kt) * 64) + lane) * 8];
    __syncthreads();                      // wfrag dead; gates alias it

    // pointwise mapping: thread = (batch pb, dim pd)
    const int pb = tid >> 3, pd = tid & 7;
    const float* bias = cell ? b1 : b0;
    const int gdim = wb * 8 + pd;
    const float bi = bias[0 * 1024 + gdim], bfg = bias[1 * 1024 + gdim],
                bg = bias[2 * 1024 + gdim], bo  = bias[3 * 1024 + gdim];
    float creg = 0.0f;                    // c-state: thread-private register

    const int kbase = kq * 256;

    for (int p = 0; p <= TSTEPS; ++p) {
        const int rd = p & 1, wr = rd ^ 1;

        const bool gemm_active = cell ? (p >= 1) : (p < TSTEPS);
        if (gemm_active) {
            #pragma unroll
            for (int mt = 0; mt < 4; ++mt) {
                const int bm = mt * 16 + n15;
                const _Float16* a;
                if (cell == 0 && kq < 4) {
                    a = xh + ((size_t)bm * TSTEPS + p) * DIM + kbase + q * 8;
                } else {
                    int layer = (cell == 0) ? 0 : (kq >> 2);
                    int kh = (cell == 0) ? (kq - 4) * 256 : (kq & 3) * 256;
                    a = hbuf + rd * 131072 + layer * 65536 + bm * 1024 + kh + q * 8;
                }
                f32x4 acc0 = {0.f, 0.f, 0.f, 0.f};
                f32x4 acc1 = {0.f, 0.f, 0.f, 0.f};
                #pragma unroll
                for (int kt = 0; kt < 8; ++kt) {
                    half8v av = *(const half8v*)(a + kt * 32);
                    acc0 = __builtin_amdgcn_mfma_f32_16x16x32_f16(av, wreg[kt],     acc0, 0, 0, 0);
                    acc1 = __builtin_amdgcn_mfma_f32_16x16x32_f16(av, wreg[8 + kt], acc1, 0, 0, 0);
                }
                const int row0 = mt * 16 + q * 4;
                #pragma unroll
                for (int r = 0; r < 4; ++r) {
                    gates[(kq * 64 + row0 + r) * GST + n15]      = acc0[r];
                    gates[(kq * 64 + row0 + r) * GST + 16 + n15] = acc1[r];
                }
            }
        }
        __syncthreads();

        const bool pw_active = cell ? (p >= 1) : (p < TSTEPS);
        if (pw_active) {
            float g0 = 0.f, g1 = 0.f, g2 = 0.f, g3 = 0.f;
            #pragma unroll
            for (int k8 = 0; k8 < 8; ++k8) {
                const float* gsr = gates + (k8 * 64 + pb) * GST + pd;
                g0 += gsr[0]; g1 += gsr[8]; g2 += gsr[16]; g3 += gsr[24];
            }
            g0 += bi; g1 += bfg; g2 += bg; g3 += bo;
            float si = 1.f / (1.f + __expf(-g0));
            float sf = 1.f / (1.f + __expf(-g1));
            float so = 1.f / (1.f + __expf(-g3));
            float cn = sf * creg + si * tanhf(g2);
            float hn = so * tanhf(cn);
            creg = cn;
            union { _Float16 h; unsigned short u; } cv; cv.h = (_Float16)hn;
            __hip_atomic_store((unsigned short*)(hbuf + wr * 131072 + cell * 65536
                                                 + pb * 1024 + gdim),
                               cv.u, __ATOMIC_RELAXED, __HIP_MEMORY_SCOPE_AGENT);
            if (cell && p == TSTEPS) out[pb * 1024 + gdim] = hn;
        }

        if (p < TSTEPS) {
            // ---- lightweight global barrier + per-phase cache invalidate ----
            asm volatile("s_waitcnt vmcnt(0)" ::: "memory");   // h stores at L3
            __syncthreads();
            if (tid == 0)
                __hip_atomic_store(&flags[blk], (unsigned)(p + 1),
                                   __ATOMIC_RELAXED, __HIP_MEMORY_SCOPE_AGENT);
            if (tid < 256) {
                const unsigned target = (unsigned)(p + 1);
                while (__hip_atomic_load(&flags[tid], __ATOMIC_RELAXED,
                                         __HIP_MEMORY_SCOPE_AGENT) < target) {}
            }
            __syncthreads();
            // make other XCDs' h stores visible to our plain cached loads
            __builtin_amdgcn_fence(__ATOMIC_ACQUIRE, "agent");
        }
    }
}

extern "C" void kernel_launch(void* const* d_in, const int* in_sizes, int n_in,
                              void* d_out, int out_size, void* d_ws, size_t ws_size,
                              hipStream_t stream)
{
    const float* x   = (const float*)d_in[0];
    const float* Wx0 = (const float*)d_in[1];
    const float* Wh0 = (const float*)d_in[2];
    const float* b0  = (const float*)d_in[3];
    const float* Wx1 = (const float*)d_in[4];
    const float* Wh1 = (const float*)d_in[5];
    const float* b1  = (const float*)d_in[6];
    float* out = (float*)d_out;

    _Float16* xh    = (_Float16*)d_ws;
    _Float16* hbuf  = xh + (size_t)16777216;
    unsigned* flags = (unsigned*)(hbuf + 262144);

    hipLaunchKernelGGL(prologue, dim3(2048), dim3(256), 0, stream, x, xh, hbuf, flags);

    size_t smem = 131072;   // wfrag staging; in-loop live: gates 71.7 KB
    (void)hipFuncSetAttribute((const void*)lstm_persistent,
                              hipFuncAttributeMaxDynamicSharedMemorySize, (int)smem);

    void* args[] = {(void*)&Wx0, (void*)&Wh0, (void*)&b0,
                    (void*)&Wx1, (void*)&Wh1, (void*)&b1,
                    (void*)&xh, (void*)&hbuf, (void*)&flags, (void*)&out};
    (void)hipLaunchCooperativeKernel((const void*)lstm_persistent, dim3(256), dim3(512),
                                     args, (unsigned)smem, stream);
}